// Round 1
// baseline (523.321 us; speedup 1.0000x reference)
//
#include <hip/hip_runtime.h>

#define TT 2048
#define BB 1024
#define H  10

// sigma(a) = 1/(1+exp(-a)); tanh(t) = 1 - 2/(1+exp(2t))
__device__ __forceinline__ float fast_sigmoid(float a) {
    float e = __expf(-a);
    return __builtin_amdgcn_rcpf(1.0f + e);
}
__device__ __forceinline__ float fast_tanh(float t) {
    float e = __expf(2.0f * t);
    return fmaf(-2.0f, __builtin_amdgcn_rcpf(1.0f + e), 1.0f);
}

// One wave64 per sequence. Lane roles per step i (layer1 skewed by 1 step,
// output head skewed by 2 steps):
//   lanes  0- 9 : dotA = a_r0[u]  = bih0_r+bhh0_r + Wih0_r*x_i + Whh0_r . h1_{i-1}
//   lanes 10-19 : dotA = a_z0[u]
//   lanes 20-29 : dotA = hn0[u]   = bhh0_n + Whh0_n . h1_{i-1}
//   lanes 30-39 : dotA = Wih1_r . h1_{i-1} (+bih1_r+bhh1_r), dotB = Whh1_r . h2_{i-2}
//   lanes 40-49 : same for z rows
//   lanes 50-59 : dotA = xn1[u] = bih1_n + Wih1_n . h1_{i-1}; dotB = hn1[u] = bhh1_n + Whh1_n . h2_{i-2}
//   lane  60    : dotB = out_{i-2} = blin + Wlin . h2_{i-2}
// Gate lanes: 0-9 = layer0 unit u, 10-19 = layer1 unit u. Gathers via ds_bpermute.
// Hidden state is wave-uniform -> SGPRs via v_readlane (20/step).
__global__ __launch_bounds__(64) void gru_wave_kernel(
    const float* __restrict__ X,
    const float* __restrict__ Wih0, const float* __restrict__ Whh0,
    const float* __restrict__ bih0, const float* __restrict__ bhh0,
    const float* __restrict__ Wih1, const float* __restrict__ Whh1,
    const float* __restrict__ bih1, const float* __restrict__ bhh1,
    const float* __restrict__ Wlin, const float* __restrict__ blin,
    float* __restrict__ OUT)
{
    const int seq = blockIdx.x;
    const int l   = threadIdx.x;   // 0..63

    float wA[H], wB[H];
    float biasA = 0.f, biasB = 0.f, wx = 0.f, wxn = 0.f, bxn = 0.f;
    #pragma unroll
    for (int k = 0; k < H; ++k) { wA[k] = 0.f; wB[k] = 0.f; }

    if (l < 30) {
        #pragma unroll
        for (int k = 0; k < H; ++k) wA[k] = Whh0[l * H + k];
        if (l < 20) { biasA = bih0[l] + bhh0[l]; wx = Wih0[l]; }
        else        { biasA = bhh0[l]; }
    } else if (l < 60) {
        int r = l - 30;
        #pragma unroll
        for (int k = 0; k < H; ++k) { wA[k] = Wih1[r * H + k]; wB[k] = Whh1[r * H + k]; }
        if (r < 20) { biasA = bih1[r] + bhh1[r]; }
        else        { biasA = bih1[r]; biasB = bhh1[r]; }
    } else if (l == 60) {
        #pragma unroll
        for (int k = 0; k < H; ++k) wB[k] = Wlin[k];
        biasB = blin[0];
    }
    if (l < 10) { wxn = Wih0[20 + l]; bxn = bih0[20 + l]; }

    // bpermute byte-address indices (precomputed, constant over the loop)
    int i1, i2, i3, i4;
    if (l < 10)      { i1 = l;      i2 = l + 10; i3 = l + 20; i4 = l; }
    else if (l < 20) { i1 = l + 20; i2 = l + 30; i3 = l + 40; i4 = l + 40; }
    else             { i1 = l; i2 = l; i3 = l; i4 = l; }
    i1 <<= 2; i2 <<= 2; i3 <<= 2; i4 <<= 2;

    const bool isP3A = (l >= 20 && l < 30);  // lanes whose published hn lives in accA
    const bool isL0g = (l < 10);
    const bool isL1g = (l >= 10 && l < 20);
    const bool is60  = (l == 60);

    // wave-uniform hidden state (SGPRs): sh1 = h1_{i-1}, sh2 = h2_{i-2}
    float sh1[H], sh2[H];
    #pragma unroll
    for (int k = 0; k < H; ++k) { sh1[k] = 0.f; sh2[k] = 0.f; }

    float hprev = 0.f;  // gate lanes: their own unit's previous hidden value

    const float* xp = X + seq * TT;
    float*       op = OUT + seq * TT;

    float4 xq = *(const float4*)xp;  // x block 0, prefetched

    // iterations 0 .. T+1 (=2050) for the 2-step pipeline; run 513 blocks of 4
    for (int ib = 0; ib < 513; ++ib) {
        int nb = 4 * (ib + 1);
        if (nb > TT - 4) nb = TT - 4;
        float4 xqn = *(const float4*)(xp + nb);   // prefetch next block
        float xs[4] = {xq.x, xq.y, xq.z, xq.w};
        #pragma unroll
        for (int u4 = 0; u4 < 4; ++u4) {
            const float x = xs[u4];
            // dotA over sh1 (split accumulators to shorten the chain)
            float a0 = fmaf(wx, x, biasA);
            float a1 = wA[5] * sh1[5];
            a0 = fmaf(wA[0], sh1[0], a0); a1 = fmaf(wA[6], sh1[6], a1);
            a0 = fmaf(wA[1], sh1[1], a0); a1 = fmaf(wA[7], sh1[7], a1);
            a0 = fmaf(wA[2], sh1[2], a0); a1 = fmaf(wA[8], sh1[8], a1);
            a0 = fmaf(wA[3], sh1[3], a0); a1 = fmaf(wA[9], sh1[9], a1);
            a0 = fmaf(wA[4], sh1[4], a0);
            float accA = a0 + a1;
            // dotB over sh2
            float b0 = fmaf(wB[0], sh2[0], biasB);
            float b1 = wB[5] * sh2[5];
            b0 = fmaf(wB[1], sh2[1], b0); b1 = fmaf(wB[6], sh2[6], b1);
            b0 = fmaf(wB[2], sh2[2], b0); b1 = fmaf(wB[7], sh2[7], b1);
            b0 = fmaf(wB[3], sh2[3], b0); b1 = fmaf(wB[8], sh2[8], b1);
            b0 = fmaf(wB[4], sh2[4], b0); b1 = fmaf(wB[9], sh2[9], b1);
            float accB = b0 + b1;

            float P1 = accA + accB;               // full pre-activation (accB==0 on L0 lanes)
            float P3 = isP3A ? accA : accB;       // hn source

            float ar  = __int_as_float(__builtin_amdgcn_ds_bpermute(i1, __float_as_int(P1)));
            float az  = __int_as_float(__builtin_amdgcn_ds_bpermute(i2, __float_as_int(P1)));
            float hn  = __int_as_float(__builtin_amdgcn_ds_bpermute(i3, __float_as_int(P3)));
            float xng = __int_as_float(__builtin_amdgcn_ds_bpermute(i4, __float_as_int(accA)));

            float xn = isL0g ? fmaf(wxn, x, bxn) : xng;
            float r  = fast_sigmoid(ar);
            float z  = fast_sigmoid(az);
            float n  = fast_tanh(fmaf(r, hn, xn));
            float hnew = fmaf(z, hprev - n, n);   // (1-z)*n + z*h

            // iteration 0 produces garbage h2_{-1} on L1 gate lanes; force 0
            if (ib == 0 && u4 == 0) { if (isL1g) hnew = 0.f; }
            hprev = hnew;

            // publish new state to wave-uniform SGPRs
            int hbits = __float_as_int(hnew);
            #pragma unroll
            for (int k = 0; k < H; ++k)
                sh1[k] = __int_as_float(__builtin_amdgcn_readlane(hbits, k));
            #pragma unroll
            for (int k = 0; k < H; ++k)
                sh2[k] = __int_as_float(__builtin_amdgcn_readlane(hbits, 10 + k));

            // output head: lane 60's accB = blin + Wlin . h2_{i-2}
            const int t = (ib * 4 + u4) - 2;
            if (is60 && t >= 0 && t < TT) op[t] = accB;
        }
        xq = xqn;
    }
}

extern "C" void kernel_launch(void* const* d_in, const int* in_sizes, int n_in,
                              void* d_out, int out_size, void* d_ws, size_t ws_size,
                              hipStream_t stream) {
    const float* X    = (const float*)d_in[0];
    const float* Wih0 = (const float*)d_in[1];
    const float* Whh0 = (const float*)d_in[2];
    const float* bih0 = (const float*)d_in[3];
    const float* bhh0 = (const float*)d_in[4];
    const float* Wih1 = (const float*)d_in[5];
    const float* Whh1 = (const float*)d_in[6];
    const float* bih1 = (const float*)d_in[7];
    const float* bhh1 = (const float*)d_in[8];
    const float* Wlin = (const float*)d_in[9];
    const float* blin = (const float*)d_in[10];

    gru_wave_kernel<<<BB, 64, 0, stream>>>(X, Wih0, Whh0, bih0, bhh0,
                                           Wih1, Whh1, bih1, bhh1, Wlin, blin,
                                           (float*)d_out);
}